// Round 14
// baseline (269.627 us; speedup 1.0000x reference)
//
#include <hip/hip_runtime.h>
#include <hip/hip_bf16.h>

#define NTOK 16384
#define HID 7168
#define NEXP 256
#define TOPK 8

typedef __bf16 bf16x8 __attribute__((ext_vector_type(8)));
typedef float  f32x16 __attribute__((ext_vector_type(16)));

typedef __attribute__((address_space(1))) const unsigned char ga_t;
typedef __attribute__((address_space(3))) unsigned char la_t;

// B bf16, phase-contiguous + LDS-swizzle pre-applied:
// layout [224 k-chunks][16 KB]; within a chunk, 16-B slot Y16 (0..1023):
//   e = Y16>>2, slot = Y16&3; holds B[e][kc*32 + (slot^(e&3))*8 .. +8]
__device__ __align__(16) unsigned short g_wb[NEXP * HID];

__device__ __forceinline__ unsigned int f2bfb(float x) {
    unsigned int u = __float_as_uint(x);
    return (u + 0x7fffu + ((u >> 16) & 1u)) >> 16;
}
__device__ __forceinline__ uint4 pk4(float4 p, float4 q) {
    uint4 u;
    u.x = f2bfb(p.x) | (f2bfb(p.y) << 16);
    u.y = f2bfb(p.z) | (f2bfb(p.w) << 16);
    u.z = f2bfb(q.x) | (f2bfb(q.y) << 16);
    u.w = f2bfb(q.z) | (f2bfb(q.w) << 16);
    return u;
}
__device__ __forceinline__ void gll16(const void* g, void* l) {
    __builtin_amdgcn_global_load_lds((ga_t*)g, (la_t*)l, 16, 0, 0);
}
__device__ __forceinline__ bf16x8 cvt8(float4 p, float4 q) {
    union { bf16x8 v; __hip_bfloat162 h[4]; } c;
    c.h[0] = __float22bfloat162_rn(make_float2(p.x, p.y));
    c.h[1] = __float22bfloat162_rn(make_float2(p.z, p.w));
    c.h[2] = __float22bfloat162_rn(make_float2(q.x, q.y));
    c.h[3] = __float22bfloat162_rn(make_float2(q.z, q.w));
    return c.v;
}

// ---- pre-convert B f32 -> bf16, phase-contiguous + pre-swizzled ----
__global__ void wconv_swz(const float* __restrict__ wt) {
    const int t   = blockIdx.x * 256 + threadIdx.x;   // 0 .. 229375 (16-B slots)
    const int y16 = t & 1023;
    const int kc  = t >> 10;                          // 0..223
    const int e   = y16 >> 2;
    const int sl  = (y16 & 3) ^ (e & 3);              // inverse swizzle at source
    const float4* s = (const float4*)(wt + (size_t)e * HID + kc * 32 + sl * 8);
    ((uint4*)g_wb)[t] = pk4(s[0], s[1]);
}

// row_idx: row[t][k] = k*NTOK + t (chunk 2)
__global__ void moe_rows(float* __restrict__ ob) {
    const int q = blockIdx.x * 256 + threadIdx.x;
    ob[262144 + q] = (float)((q & 7) * NTOK + (q >> 3));
}

// ---- gate: grid (256, KS); block 256 thr = 4 waves; wave = 32 tok x 128 exp.
// LDS 48 KB: A f32 dbuf 2x8 KB @0, B bf16 dbuf 2x16 KB @16384. 3 blocks/CU.
// Writes f32 partial logits pw[by][tok][e].
template<int KS>
__global__ __launch_bounds__(256, 3) void moe_gate_v14(
    const float* __restrict__ hs,
    float* __restrict__ pw)
{
    constexpr int KLEN = HID / KS;
    constexpr int NPH  = KLEN / 32;
    __shared__ __align__(16) char smem[49152];

    const int tid   = threadIdx.x;
    const int lane  = tid & 63;
    const int w     = tid >> 6;       // 0..3
    const int tg    = w >> 1;         // token half
    const int h     = w & 1;          // expert half
    const int t0    = blockIdx.x * 64;
    const int by    = blockIdx.y;
    const int khalf = lane >> 5;

    // A gll sources (pre-swizzled): wave instr ii covers rows (w*2+ii)*8 .. +8
    const char* aS[2];
    #pragma unroll
    for (int ii = 0; ii < 2; ++ii) {
        const int row  = (w * 2 + ii) * 8 + (lane >> 3);
        const int aoff = (((lane & 7) ^ ((lane >> 3) & 7)) << 4);
        aS[ii] = (const char*)hs + (size_t)(t0 + row) * (HID * 4)
               + (size_t)by * (KLEN * 4) + aoff;
    }
    // B gll source (linear; swizzle baked into g_wb)
    const char* bS = (const char*)g_wb + (size_t)by * NPH * 16384
                   + (w * 4) * 1024 + lane * 16;

    f32x16 acc0 = {}, acc1 = {}, acc2 = {}, acc3 = {};

    auto ISSUE = [&](int p, int bi) {
        char* bA = smem + bi * 8192;
        char* bB = smem + 16384 + bi * 16384;
        #pragma unroll
        for (int ii = 0; ii < 2; ++ii)
            gll16(aS[ii] + (size_t)p * 128, bA + (w * 2 + ii) * 1024);
        #pragma unroll
        for (int iv = 0; iv < 4; ++iv)
            gll16(bS + (size_t)p * 16384 + iv * 1024, bB + (w * 4 + iv) * 1024);
    };

    const int rowA = tg * 32 + (lane & 31);
    const int aswz = (rowA & 7) << 4;
    const int e0   = h * 128 + (lane & 31);
    const int bswz = (e0 & 3) << 4;

    auto COMPUTE = [&](int bi) {
        const char* bA = smem + bi * 8192;
        const char* bB = smem + 16384 + bi * 16384;
        #pragma unroll
        for (int s = 0; s < 2; ++s) {
            const int ca = s * 64 + khalf * 32;
            float4 a0 = *(const float4*)(bA + rowA * 128 + ((ca     ) ^ aswz));
            float4 a1 = *(const float4*)(bA + rowA * 128 + ((ca + 16) ^ aswz));
            bf16x8 a = cvt8(a0, a1);
            const int cb = (s * 32 + khalf * 16) ^ bswz;
            bf16x8 b0 = *(const bf16x8*)(bB + (e0      ) * 64 + cb);
            bf16x8 b1 = *(const bf16x8*)(bB + (e0 + 32 ) * 64 + cb);
            bf16x8 b2 = *(const bf16x8*)(bB + (e0 + 64 ) * 64 + cb);
            bf16x8 b3 = *(const bf16x8*)(bB + (e0 + 96 ) * 64 + cb);
            acc0 = __builtin_amdgcn_mfma_f32_32x32x16_bf16(a, b0, acc0, 0, 0, 0);
            acc1 = __builtin_amdgcn_mfma_f32_32x32x16_bf16(a, b1, acc1, 0, 0, 0);
            acc2 = __builtin_amdgcn_mfma_f32_32x32x16_bf16(a, b2, acc2, 0, 0, 0);
            acc3 = __builtin_amdgcn_mfma_f32_32x32x16_bf16(a, b3, acc3, 0, 0, 0);
        }
    };

    // ---- pipelined loop: gll depth-1-ahead, counted vmcnt(6), 2 barriers/phase ----
    ISSUE(0, 0);
    for (int p = 0; p < NPH - 1; ++p) {
        ISSUE(p + 1, (p + 1) & 1);
        asm volatile("s_waitcnt vmcnt(6)" ::: "memory");   // own phase-p glls done
        __builtin_amdgcn_sched_barrier(0);
        __builtin_amdgcn_s_barrier();                      // all waves' glls done
        __builtin_amdgcn_sched_barrier(0);
        COMPUTE(p & 1);
        __builtin_amdgcn_s_barrier();                      // reads done -> buf reusable
        __builtin_amdgcn_sched_barrier(0);
    }
    asm volatile("s_waitcnt vmcnt(0)" ::: "memory");
    __builtin_amdgcn_sched_barrier(0);
    __builtin_amdgcn_s_barrier();
    __builtin_amdgcn_sched_barrier(0);
    COMPUTE((NPH - 1) & 1);

    // ---- epilogue: write partial logits (f32) straight to workspace ----
    float* base = pw + ((size_t)by * NTOK + t0) * 256;
    #pragma unroll
    for (int r = 0; r < 16; ++r) {
        const int tok = tg * 32 + (r & 3) + 8 * (r >> 2) + 4 * khalf;
        float* rp = base + (size_t)tok * 256 + h * 128 + (lane & 31);
        rp[0]  = acc0[r];
        rp[32] = acc1[r];
        rp[64] = acc2[r];
        rp[96] = acc3[r];
    }
}

// ---- reduce: sum KS planes, top-8 + renormalized softmax ----
template<int KS>
__global__ __launch_bounds__(256) void moe_reduce(
    const float* __restrict__ pw,
    float* __restrict__ ob)
{
    __shared__ float ll[64 * 257];
    const int tid = threadIdx.x;
    const size_t ro = (size_t)blockIdx.x * 16384;        // 64 tok x 256 exp
    const size_t PS = (size_t)NTOK * 256;

    #pragma unroll
    for (int j = 0; j < 16; ++j) {
        const size_t f = (size_t)j * 1024 + tid * 4;
        float4 v = *(const float4*)(pw + ro + f);
        #pragma unroll
        for (int s = 1; s < KS; ++s) {
            float4 u = *(const float4*)(pw + s * PS + ro + f);
            v.x += u.x; v.y += u.y; v.z += u.z; v.w += u.w;
        }
        const int t = (int)(f >> 8);
        const int e = (int)(f & 255);
        *(float4*)&ll[t * 257 + e] = v;
    }
    __syncthreads();

    if (tid < 64) {
        const float* lr = ll + tid * 257;
        float bv[TOPK]; int bi8[TOPK];
        #pragma unroll
        for (int k = 0; k < TOPK; ++k) { bv[k] = -1e30f; bi8[k] = 0; }
        for (int e = 0; e < NEXP; ++e) {
            const float v = lr[e];
            if (v > bv[TOPK - 1]) {
                int k = TOPK - 1;
                while (k > 0 && v > bv[k - 1]) {
                    bv[k] = bv[k - 1]; bi8[k] = bi8[k - 1]; --k;
                }
                bv[k] = v; bi8[k] = e;      // strict > : ties keep lower idx
            }
        }
        float ev[TOPK], ssum = 0.f;
        #pragma unroll
        for (int r = 0; r < TOPK; ++r) { ev[r] = expf(bv[r] - bv[0]); ssum += ev[r]; }
        const float inv = 1.0f / ssum;

        const int tg = blockIdx.x * 64 + tid;
        #pragma unroll
        for (int r = 0; r < TOPK; ++r) {
            ob[(size_t)tg * TOPK + r]          = (float)bi8[r];   // idx
            ob[131072 + (size_t)tg * TOPK + r] = ev[r] * inv;     // weight
        }
    }
}

extern "C" void kernel_launch(void* const* d_in, const int* in_sizes, int n_in,
                              void* d_out, int out_size, void* d_ws, size_t ws_size,
                              hipStream_t stream) {
    const float* hs = (const float*)d_in[0];   // [16384, 7168] f32
    const float* wt = (const float*)d_in[1];   // [256, 7168] f32
    float* ob = (float*)d_out;                 // f32[393216]: idx | weight | row
    float* pw = (float*)d_ws;

    wconv_swz<<<dim3(NEXP * HID * 2 / 16 / 256), dim3(256), 0, stream>>>(wt);

    const size_t need4 = (size_t)4 * NTOK * NEXP * sizeof(float);   // 64 MB
    if (ws_size >= need4) {
        moe_gate_v14<4><<<dim3(256, 4), dim3(256), 0, stream>>>(hs, pw);
        moe_reduce<4><<<dim3(256), dim3(256), 0, stream>>>(pw, ob);
    } else {
        moe_gate_v14<1><<<dim3(256, 1), dim3(256), 0, stream>>>(hs, pw);
        moe_reduce<1><<<dim3(256), dim3(256), 0, stream>>>(pw, ob);
    }
    moe_rows<<<dim3(512), dim3(256), 0, stream>>>(ob);
}

// Round 15
// 243.641 us; speedup vs baseline: 1.1067x; 1.1067x over previous
//
#include <hip/hip_runtime.h>
#include <hip/hip_bf16.h>

#define NTOK 16384
#define HID 7168
#define NEXP 256
#define TOPK 8

#define BT 32                  // tokens per block
#define NIT 112                // K iterations (BK=64)

typedef __bf16 bf16x8 __attribute__((ext_vector_type(8)));
typedef float  f32x16 __attribute__((ext_vector_type(16)));

// Weights, MFMA-fragment-linear (R12-proven layout):
// uint4 idx = ((p8*8 + g)*8 + ks)*64 + lane holds
// B[e = g*32 + (lane&31)][k = p8*128 + ks*16 + (lane>>5)*8 .. +8]
__device__ __align__(16) unsigned short g_wb[NEXP * HID];

__device__ __forceinline__ unsigned int f2bfb(float x) {
    unsigned int u = __float_as_uint(x);
    return (u + 0x7fffu + ((u >> 16) & 1u)) >> 16;
}
__device__ __forceinline__ uint4 pk4(float4 p, float4 q) {
    uint4 u;
    u.x = f2bfb(p.x) | (f2bfb(p.y) << 16);
    u.y = f2bfb(p.z) | (f2bfb(p.w) << 16);
    u.z = f2bfb(q.x) | (f2bfb(q.y) << 16);
    u.w = f2bfb(q.z) | (f2bfb(q.w) << 16);
    return u;
}
__device__ __forceinline__ bf16x8 asbf8(uint4 u) {
    union { uint4 a; bf16x8 b; } c; c.a = u; return c.b;
}

__global__ void wconv_frag(const float* __restrict__ wt) {
    const int tid = blockIdx.x * 256 + threadIdx.x;
    const int l  = tid & 63;
    const int ks = (tid >> 6) & 7;
    const int g  = (tid >> 9) & 7;
    const int p  = tid >> 12;
    const int e  = g * 32 + (l & 31);
    const int kb = p * 128 + ks * 16 + ((l >> 5) << 3);
    const float4* s = (const float4*)(wt + (size_t)e * HID + kb);
    ((uint4*)g_wb)[tid] = pk4(s[0], s[1]);
}

__global__ void moe_rows(float* __restrict__ ob) {
    const int q = blockIdx.x * 256 + threadIdx.x;
    ob[262144 + q] = (float)((q & 7) * NTOK + (q >> 3));
}

// Block 512 thr = 8 waves; wave w: 32 tokens x experts [w*32, w*32+32).
// A: LDS bf16 tri-buffer 3 x 4 KB (async-split staging). B: regs from g_wb.
// LDS 33.8 KB; epilogue aliases logits [32][257] f32 over it.
__global__ __launch_bounds__(512, 4) void moe_gate_v15(
    const float* __restrict__ hs,
    float* __restrict__ ob)
{
    __shared__ __align__(16) char smem[33792];

    const int tid   = threadIdx.x;
    const int lane  = tid & 63;
    const int w     = tid >> 6;       // 0..7 = expert group
    const int khalf = lane >> 5;
    const int t0    = blockIdx.x * BT;

    // A staging: thread loads hs[t0 + (tid>>4)][s*64 + (tid&15)*4 .. +4]
    const int ar = tid >> 4;          // 0..31
    const int ac = tid & 15;          // 0..15
    const float* aload = hs + (size_t)(t0 + ar) * HID + ac * 4;
    const int awb = (ac >> 1) * 512 + ar * 16 + (ac & 1) * 8;   // bf16 dest byte

    // A fragment read: conflict-free contiguous (lanes 0..31 adjacent 16B)
    const int arb = (lane & 31) * 16;

    // B fragment-linear base for this wave's expert group
    const char* const bbase = (const char*)g_wb + w * 8192 + lane * 16;

    f32x16 acc = {};
    uint4 bA0, bA1, bA2, bA3;   // B set A
    uint4 bB0, bB1, bB2, bB3;   // B set B

    char* p0 = smem;            // read buf (iter s)
    char* p1 = smem + 4096;     // iter s+1
    char* p2 = smem + 8192;     // write target (iter s+2)

#define LOADB(SET, S)                                                         \
    do {                                                                      \
        const char* bp = bbase + (size_t)((S) >> 1) * 65536 + ((S) & 1) * 4096; \
        b##SET##0 = *(const uint4*)(bp);                                      \
        b##SET##1 = *(const uint4*)(bp + 1024);                               \
        b##SET##2 = *(const uint4*)(bp + 2048);                               \
        b##SET##3 = *(const uint4*)(bp + 3072);                               \
    } while (0)

#define WRITEA(V, BUF)                                                        \
    do {                                                                      \
        uint2 u;                                                              \
        u.x = f2bfb((V).x) | (f2bfb((V).y) << 16);                            \
        u.y = f2bfb((V).z) | (f2bfb((V).w) << 16);                            \
        *(uint2*)((BUF) + awb) = u;                                           \
    } while (0)

#define COMPUTE(BUF, SET)                                                     \
    do {                                                                      \
        bf16x8 a;                                                             \
        a = *(const bf16x8*)((BUF) + (0 * 2 + khalf) * 512 + arb);            \
        acc = __builtin_amdgcn_mfma_f32_32x32x16_bf16(a, asbf8(b##SET##0), acc, 0, 0, 0); \
        a = *(const bf16x8*)((BUF) + (1 * 2 + khalf) * 512 + arb);            \
        acc = __builtin_amdgcn_mfma_f32_32x32x16_bf16(a, asbf8(b##SET##1), acc, 0, 0, 0); \
        a = *(const bf16x8*)((BUF) + (2 * 2 + khalf) * 512 + arb);            \
        acc = __builtin_amdgcn_mfma_f32_32x32x16_bf16(a, asbf8(b##SET##2), acc, 0, 0, 0); \
        a = *(const bf16x8*)((BUF) + (3 * 2 + khalf) * 512 + arb);            \
        acc = __builtin_amdgcn_mfma_f32_32x32x16_bf16(a, asbf8(b##SET##3), acc, 0, 0, 0); \
    } while (0)

    // ---- prologue: A(0)->p0, A(1)->p1, B(0)->setA ----
    {
        float4 v0 = *(const float4*)(aload);
        float4 v1 = *(const float4*)(aload + 64);
        WRITEA(v0, p0);
        WRITEA(v1, p1);
    }
    LOADB(A, 0);
    __syncthreads();

    // ---- main loop: x2 unrolled; 1 sync/iter; A 2-ahead, B 1-ahead ----
    for (int s = 0; s < NIT; s += 2) {
        // iter s (read p0, set A)
        float4 vA;
        const bool ldA = (s + 2 < NIT);
        if (ldA) vA = *(const float4*)(aload + (size_t)(s + 2) * 64);
        LOADB(B, s + 1);
        COMPUTE(p0, A);
        __syncthreads();
        if (ldA) WRITEA(vA, p2);

        // iter s+1 (read p1, set B)
        float4 vB;
        const bool ldB = (s + 3 < NIT);
        if (ldB) vB = *(const float4*)(aload + (size_t)(s + 3) * 64);
        if (s + 2 < NIT) LOADB(A, s + 2);
        COMPUTE(p1, B);
        __syncthreads();
        if (ldB) WRITEA(vB, p0);

        // rotate: (p0,p1,p2) <- (p2,p0,p1)
        char* t = p2; p2 = p1; p1 = p0; p0 = t;
    }

    // ---- epilogue: logits [32][257] f32 aliased over smem ----
    float* ll = (float*)smem;
    {
        const int ec = w * 32 + (lane & 31);
        #pragma unroll
        for (int r = 0; r < 16; ++r) {
            const int tok = (r & 3) + 8 * (r >> 2) + 4 * khalf;
            ll[tok * 257 + ec] = acc[r];
        }
    }
    __syncthreads();

    if (tid < BT) {
        const float* lr = ll + tid * 257;
        float bv[TOPK]; int bi8[TOPK];
        #pragma unroll
        for (int k = 0; k < TOPK; ++k) { bv[k] = -1e30f; bi8[k] = 0; }
        for (int e = 0; e < NEXP; ++e) {
            const float v = lr[e];
            if (v > bv[TOPK - 1]) {
                int k = TOPK - 1;
                while (k > 0 && v > bv[k - 1]) {
                    bv[k] = bv[k - 1]; bi8[k] = bi8[k - 1]; --k;
                }
                bv[k] = v; bi8[k] = e;      // strict > : ties keep lower idx
            }
        }
        float ev[TOPK], ssum = 0.f;
        #pragma unroll
        for (int r = 0; r < TOPK; ++r) { ev[r] = expf(bv[r] - bv[0]); ssum += ev[r]; }
        const float inv = 1.0f / ssum;

        const int tg = t0 + tid;
        #pragma unroll
        for (int r = 0; r < TOPK; ++r) {
            ob[(size_t)tg * TOPK + r]          = (float)bi8[r];   // idx
            ob[131072 + (size_t)tg * TOPK + r] = ev[r] * inv;     // weight
        }
    }
#undef LOADB
#undef WRITEA
#undef COMPUTE
}

extern "C" void kernel_launch(void* const* d_in, const int* in_sizes, int n_in,
                              void* d_out, int out_size, void* d_ws, size_t ws_size,
                              hipStream_t stream) {
    const float* hs = (const float*)d_in[0];   // [16384, 7168] f32
    const float* wt = (const float*)d_in[1];   // [256, 7168] f32
    float* ob = (float*)d_out;                 // f32[393216]: idx | weight | row

    wconv_frag<<<dim3(NEXP * HID / 8 / 256), dim3(256), 0, stream>>>(wt);
    moe_gate_v15<<<dim3(NTOK / BT), dim3(512), 0, stream>>>(hs, ob);
    moe_rows<<<dim3(512), dim3(256), 0, stream>>>(ob);
}